// Round 5
// baseline (602.891 us; speedup 1.0000x reference)
//
#include <hip/hip_runtime.h>
#include <hip/hip_cooperative_groups.h>
#include <stdint.h>

namespace cg = cooperative_groups;

// Problem dims: x(4,2048,512) W1(512,1024) b1(1024) Wq(1024,1024) A=16 — fp32 in, fp32 out
constexpr int BATCH = 4;
constexpr int SEQ   = 2048;
constexpr int DIN   = 512;
constexpr int DH    = 1024;
constexpr int BS    = BATCH * SEQ;  // 8192
constexpr int AP    = 32;           // attn positions per block
constexpr int AW    = 64;           // attn window rows (AP + 2*16)

typedef float  floatx4 __attribute__((ext_vector_type(4)));
typedef short  bf16x8  __attribute__((ext_vector_type(8)));

static __device__ __forceinline__ unsigned short f2bf(float f) {
  union { float f; unsigned u; } v; v.f = f;
  unsigned r = (v.u + 0x7fffu + ((v.u >> 16) & 1u)) >> 16;  // RNE
  return (unsigned short)r;
}

// async global->LDS, 16B per lane; LDS dest is wave-uniform base + lane*16
static __device__ __forceinline__ void gld_lds16(const unsigned short* g, const short* l) {
  typedef const __attribute__((address_space(1))) void* gvp;
  typedef __attribute__((address_space(3))) void* lvp;
  __builtin_amdgcn_global_load_lds((gvp)(uintptr_t)g, (lvp)(unsigned)(uintptr_t)l, 16, 0, 0);
}

// ---------------- 16-wave 128x128 GEMM tile (BK=64 as two 32-halves) --------------------
// Waves 0-7 stage A (16 rows each), waves 8-15 stage B. Wave grid 4x4, 32x32 out/wave.
// bias != null => +bias, relu. outBT != null => also store transposed [N][M].
static __device__ __forceinline__ void do_gemm(
    const unsigned short* __restrict__ Ab, const unsigned short* __restrict__ Bt,
    const float* __restrict__ bias, unsigned short* __restrict__ outB,
    unsigned short* __restrict__ outBT, int M, int N, int K, int m0, int n0,
    int tid, char* smemc) {
  short (*Sm)[128 * 32] = (short (*)[128 * 32])smemc;  // [0,1]=A k-halves, [2,3]=B
  const int wv = tid >> 6, lane = tid & 63;
  const int wm = (wv >> 2) * 32, wn = (wv & 3) * 32;
  const int l16 = lane & 15, quad = lane >> 4;
  const int ra = lane >> 2, ca = (lane & 3) * 8;
  const int wA = wv & 7;
  const bool isB = wv >= 8;
  const unsigned short* gS =
      (isB ? Bt + (size_t)(n0 + wA * 16 + ra) * K : Ab + (size_t)(m0 + wA * 16 + ra) * K) + ca;
  const short* l0 = &Sm[isB ? 2 : 0][wA * 512];
  const short* l1 = &Sm[isB ? 3 : 1][wA * 512];

  floatx4 acc[2][2];
  for (int i = 0; i < 2; i++)
    for (int j = 0; j < 2; j++) acc[i][j] = {0.f, 0.f, 0.f, 0.f};

  for (int ks = 0; ks < K / 64; ++ks) {
    __syncthreads();  // prev iter LDS reads done
    gld_lds16(gS, l0);
    gld_lds16(gS + 32, l1);
    gS += 64;
    __syncthreads();  // drains vmcnt
    bf16x8 a0 = *(const bf16x8*)&Sm[0][(wm + l16) * 32 + quad * 8];
    bf16x8 a1 = *(const bf16x8*)&Sm[0][(wm + 16 + l16) * 32 + quad * 8];
    bf16x8 b0 = *(const bf16x8*)&Sm[2][(wn + l16) * 32 + quad * 8];
    bf16x8 b1 = *(const bf16x8*)&Sm[2][(wn + 16 + l16) * 32 + quad * 8];
    acc[0][0] = __builtin_amdgcn_mfma_f32_16x16x32_bf16(a0, b0, acc[0][0], 0, 0, 0);
    acc[0][1] = __builtin_amdgcn_mfma_f32_16x16x32_bf16(a0, b1, acc[0][1], 0, 0, 0);
    acc[1][0] = __builtin_amdgcn_mfma_f32_16x16x32_bf16(a1, b0, acc[1][0], 0, 0, 0);
    acc[1][1] = __builtin_amdgcn_mfma_f32_16x16x32_bf16(a1, b1, acc[1][1], 0, 0, 0);
    a0 = *(const bf16x8*)&Sm[1][(wm + l16) * 32 + quad * 8];
    a1 = *(const bf16x8*)&Sm[1][(wm + 16 + l16) * 32 + quad * 8];
    b0 = *(const bf16x8*)&Sm[3][(wn + l16) * 32 + quad * 8];
    b1 = *(const bf16x8*)&Sm[3][(wn + 16 + l16) * 32 + quad * 8];
    acc[0][0] = __builtin_amdgcn_mfma_f32_16x16x32_bf16(a0, b0, acc[0][0], 0, 0, 0);
    acc[0][1] = __builtin_amdgcn_mfma_f32_16x16x32_bf16(a0, b1, acc[0][1], 0, 0, 0);
    acc[1][0] = __builtin_amdgcn_mfma_f32_16x16x32_bf16(a1, b0, acc[1][0], 0, 0, 0);
    acc[1][1] = __builtin_amdgcn_mfma_f32_16x16x32_bf16(a1, b1, acc[1][1], 0, 0, 0);
  }

  // epilogue: C row = m0+wm+i*16+quad*4+r, col = n0+wn+j*16+l16 (m89-verified layout)
  for (int j = 0; j < 2; j++) {
    const int col = n0 + wn + j * 16 + l16;
    const float bv = bias ? bias[col] : 0.f;
    for (int i = 0; i < 2; i++) {
      const int rowb = m0 + wm + i * 16 + quad * 4;
      float v[4];
      for (int r = 0; r < 4; r++) {
        float t = acc[i][j][r] + bv;
        v[r] = bias ? fmaxf(t, 0.f) : t;
      }
      for (int r = 0; r < 4; r++) outB[(size_t)(rowb + r) * N + col] = f2bf(v[r]);
      if (outBT) {
        ushort4 o4;
        o4.x = f2bf(v[0]); o4.y = f2bf(v[1]); o4.z = f2bf(v[2]); o4.w = f2bf(v[3]);
        *(ushort4*)(outBT + (size_t)col * M + rowb) = o4;
      }
    }
  }
}

// ---------------- cooperative mega-kernel: prep -> gemm1 -> gemm2 -> attn ---------------
// Grid = 256 blocks x 1024 threads, 1 block/CU (cooperative co-residency).
__global__ __launch_bounds__(1024, 4) void mega_k(
    const float* X, const float* W1g, const float* b1v, const float* Wqg,
    unsigned short* xb, unsigned short* w1t, unsigned short* wqt,
    unsigned short* hb, unsigned short* hbT, unsigned short* qb, float* out) {
  __shared__ __align__(16) char smem[32768];
  const int tid = threadIdx.x;
  const int bid = blockIdx.x;
  cg::grid_group grid = cg::this_grid();

  // ======== phase 0: X fp32->bf16 + W1/Wq transposes ========
  {
    const int gtid = bid * 1024 + tid;
    #pragma unroll
    for (int k = 0; k < 2; k++) {
      const size_t t0 = (size_t)gtid + (size_t)k * 262144;  // 524288 items of 8 floats
      const float4 a = ((const float4*)X)[t0 * 2];
      const float4 b = ((const float4*)X)[t0 * 2 + 1];
      __align__(16) unsigned short o[8];
      o[0] = f2bf(a.x); o[1] = f2bf(a.y); o[2] = f2bf(a.z); o[3] = f2bf(a.w);
      o[4] = f2bf(b.x); o[5] = f2bf(b.y); o[6] = f2bf(b.z); o[7] = f2bf(b.w);
      *(uint4*)(xb + t0 * 8) = *(const uint4*)o;
    }
    // 1536 32x32 transpose tiles; 4 sub-groups of 256 threads; uniform trip count per block
    float (*tt)[33] = (float (*)[33])(smem + (tid >> 8) * 4224);
    const int stid = tid & 255;
    const int tx = stid & 31, ty = stid >> 5;
    for (int t = bid * 4 + (tid >> 8); t < 1536; t += 1024) {
      const int by = t >> 5, bx = t & 31;
      const bool isW1 = by < 16;
      const float* in = isW1 ? W1g : Wqg;
      unsigned short* ow = isW1 ? w1t : wqt;
      const int R = isW1 ? DIN : DH;
      const int r0 = (isW1 ? by : by - 16) * 32;
      const int c0 = bx * 32;
      __syncthreads();
      for (int i = ty; i < 32; i += 8) tt[i][tx] = in[(size_t)(r0 + i) * DH + c0 + tx];
      __syncthreads();
      for (int i = ty; i < 32; i += 8) ow[(size_t)(c0 + i) * R + r0 + tx] = f2bf(tt[tx][i]);
    }
  }
  __threadfence();
  grid.sync();

  // ======== phase 1: h = relu(xb @ W1 + b1) -> hb, hbT (512 tiles, 2 per block) ========
  for (int t = bid; t < 512; t += 256)
    do_gemm(xb, w1t, b1v, hb, hbT, BS, DH, DIN, (t & 63) * 128, (t >> 6) * 128, tid, smem);
  __threadfence();
  grid.sync();

  // ======== phase 2: q = hb @ Wq -> qb ========
  for (int t = bid; t < 512; t += 256)
    do_gemm(hb, wqt, nullptr, qb, nullptr, BS, DH, DH, (t & 63) * 128, (t >> 6) * 128, tid, smem);
  __threadfence();
  grid.sync();

  // ======== phase 3: banded attention (16 waves, p0 = bid*32) ========
  {
    float* Sf = (float*)smem;                  // [2][32*64] partials per K-half
    short* Ps = (short*)(smem + 16384);        // [32*72] softmax weights
    const int wave = tid >> 6, lane = tid & 63;
    const int l16 = lane & 15, quad = lane >> 4;
    const int p0 = bid * AP;
    const int s0 = p0 & (SEQ - 1);

    for (int i = tid; i < 1152; i += 1024) ((unsigned*)(smem + 16384))[i] = 0;

    // ---- QK: S[32x64] = q . h_win, K=1024 split across wave pairs ----
    {
      const int kh = wave & 1;         // K half
      const int nt = (wave >> 1) & 3;  // window col tile
      const int mt = wave >> 3;        // pos row tile
      const unsigned short* qp = qb + (size_t)(p0 + mt * 16 + l16) * DH + kh * 512 + quad * 8;
      const int hrow = s0 - 16 + nt * 16 + l16;
      const bool hv = (hrow >= 0) && (hrow < SEQ);
      const unsigned short* hp =
          hb + (long long)(p0 - 16 + nt * 16 + l16) * DH + kh * 512 + quad * 8;

      floatx4 ac[4] = {{0,0,0,0},{0,0,0,0},{0,0,0,0},{0,0,0,0}};
      const bf16x8 hz = {0,0,0,0,0,0,0,0};
      __builtin_amdgcn_s_setprio(1);
      #pragma unroll
      for (int it = 0; it < 16; ++it) {  // K = 512 per wave
        bf16x8 qa = *(const bf16x8*)(qp + it * 32);
        bf16x8 ha = hz;
        if (hv) ha = *(const bf16x8*)(hp + it * 32);
        ac[it & 3] = __builtin_amdgcn_mfma_f32_16x16x32_bf16(qa, ha, ac[it & 3], 0, 0, 0);
      }
      __builtin_amdgcn_s_setprio(0);
      floatx4 s4;
      for (int r = 0; r < 4; r++) s4[r] = (ac[0][r] + ac[1][r]) + (ac[2][r] + ac[3][r]);
      for (int r = 0; r < 4; r++)
        Sf[kh * 2048 + (mt * 16 + quad * 4 + r) * 64 + nt * 16 + l16] = s4[r] * (1.f / 32.f);
    }
    __syncthreads();

    // ---- softmax over the 33 band entries jj = row..row+32 ----
    if (tid < 512) {
      const int row = tid >> 4, k = tid & 15;
      const float v0 = Sf[row * 64 + row + k] + Sf[2048 + row * 64 + row + k];
      const float v1 = Sf[row * 64 + row + k + 16] + Sf[2048 + row * 64 + row + k + 16];
      const float v2 = (k == 0) ? (Sf[row * 64 + row + 32] + Sf[2048 + row * 64 + row + 32])
                                : -1e30f;
      float mx = fmaxf(v0, fmaxf(v1, v2));
      for (int off = 1; off < 16; off <<= 1) mx = fmaxf(mx, __shfl_xor(mx, off, 64));
      const float e0 = __expf(v0 - mx), e1 = __expf(v1 - mx);
      const float e2 = (k == 0) ? __expf(v2 - mx) : 0.f;
      float sum = e0 + e1 + e2;
      for (int off = 1; off < 16; off <<= 1) sum += __shfl_xor(sum, off, 64);
      const float inv = 1.f / sum;
      Ps[row * 72 + row + k] = f2bf(e0 * inv);
      Ps[row * 72 + row + k + 16] = f2bf(e1 * inv);
      if (k == 0) Ps[row * 72 + row + 32] = f2bf(e2 * inv);
    }
    __syncthreads();

    // ---- PV (transposed): D[dh, pos] = Hwin^T @ P^T, 4 dh-tiles per wave ----
    {
      const bf16x8 pb00 = *(const bf16x8*)&Ps[(l16) * 72 + quad * 8];
      const bf16x8 pb01 = *(const bf16x8*)&Ps[(l16) * 72 + 32 + quad * 8];
      const bf16x8 pb10 = *(const bf16x8*)&Ps[(16 + l16) * 72 + quad * 8];
      const bf16x8 pb11 = *(const bf16x8*)&Ps[(16 + l16) * 72 + 32 + quad * 8];

      int lo = 16 - s0; if (lo < 0) lo = 0;
      int hi = SEQ + 16 - s0; if (hi > AW) hi = AW;
      const bool interior = (lo == 0) && (hi == AW);

      #pragma unroll
      for (int i = 0; i < 4; ++i) {
        const int mt2 = wave * 4 + i;  // dh tile (0..63)
        const unsigned short* ap = hbT + (size_t)(mt2 * 16 + l16) * BS + (p0 - 16) + quad * 8;
        bf16x8 aa0 = *(const bf16x8*)(ap);
        bf16x8 aa1 = *(const bf16x8*)(ap + 32);
        if (!interior) {
          #pragma unroll
          for (int j = 0; j < 8; j++) {
            const int k = quad * 8 + j;
            if (k < lo || k >= hi) aa0[j] = 0;
            if (k + 32 < lo || k + 32 >= hi) aa1[j] = 0;
          }
        }
        floatx4 o0 = {0.f, 0.f, 0.f, 0.f}, o1 = {0.f, 0.f, 0.f, 0.f};
        __builtin_amdgcn_s_setprio(1);
        o0 = __builtin_amdgcn_mfma_f32_16x16x32_bf16(aa0, pb00, o0, 0, 0, 0);
        o0 = __builtin_amdgcn_mfma_f32_16x16x32_bf16(aa1, pb01, o0, 0, 0, 0);
        o1 = __builtin_amdgcn_mfma_f32_16x16x32_bf16(aa0, pb10, o1, 0, 0, 0);
        o1 = __builtin_amdgcn_mfma_f32_16x16x32_bf16(aa1, pb11, o1, 0, 0, 0);
        __builtin_amdgcn_s_setprio(0);
        float4 s0v; s0v.x = o0[0]; s0v.y = o0[1]; s0v.z = o0[2]; s0v.w = o0[3];
        float4 s1v; s1v.x = o1[0]; s1v.y = o1[1]; s1v.z = o1[2]; s1v.w = o1[3];
        *(float4*)(out + (size_t)(p0 + l16) * DH + mt2 * 16 + quad * 4) = s0v;
        *(float4*)(out + (size_t)(p0 + 16 + l16) * DH + mt2 * 16 + quad * 4) = s1v;
      }
    }
  }
}

extern "C" void kernel_launch(void* const* d_in, const int* in_sizes, int n_in,
                              void* d_out, int out_size, void* d_ws, size_t ws_size,
                              hipStream_t stream) {
  const float* x  = (const float*)d_in[0];
  const float* W1 = (const float*)d_in[1];
  const float* b1 = (const float*)d_in[2];
  const float* Wq = (const float*)d_in[3];

  // workspace layout (51 MB total)
  char* w = (char*)d_ws;
  unsigned short* w1t = (unsigned short*)(w);                  // 1 MB  W1^T bf16
  unsigned short* wqt = (unsigned short*)(w + (1ull  << 20));  // 2 MB  Wq^T bf16
  unsigned short* hb  = (unsigned short*)(w + (3ull  << 20));  // 16 MB h bf16 row-major
  unsigned short* hbT = (unsigned short*)(w + (19ull << 20));  // 16 MB h bf16 transposed [DH][BS]
  unsigned short* qb  = (unsigned short*)(w + (35ull << 20));  // 16 MB q bf16 row-major
  // xb (8 MB, x in bf16) ALIASES qb: xb dead before phase-2 writes qb (grid.sync between)
  unsigned short* xb  = qb;
  float* outp = (float*)d_out;

  void* args[] = {(void*)&x,  (void*)&W1,  (void*)&b1,  (void*)&Wq,
                  (void*)&xb, (void*)&w1t, (void*)&wqt,
                  (void*)&hb, (void*)&hbT, (void*)&qb,  (void*)&outp};
  hipLaunchCooperativeKernel(mega_k, dim3(256), dim3(1024), args, 0, stream);
}

// Round 6
// 155.117 us; speedup vs baseline: 3.8867x; 3.8867x over previous
//
#include <hip/hip_runtime.h>
#include <stdint.h>

// Problem dims: x(4,2048,512) W1(512,1024) b1(1024) Wq(1024,1024) A=16 — fp32 in, fp32 out
constexpr int BATCH = 4;
constexpr int SEQ   = 2048;
constexpr int DIN   = 512;
constexpr int DH    = 1024;
constexpr int BS    = BATCH * SEQ;  // 8192
constexpr int AP    = 32;           // attn positions per block
constexpr int AW    = 64;           // attn window rows (AP + 2*16)

typedef float  floatx4 __attribute__((ext_vector_type(4)));
typedef short  bf16x8  __attribute__((ext_vector_type(8)));

static __device__ __forceinline__ unsigned short f2bf(float f) {
  union { float f; unsigned u; } v; v.f = f;
  unsigned r = (v.u + 0x7fffu + ((v.u >> 16) & 1u)) >> 16;  // RNE
  return (unsigned short)r;
}

// async global->LDS, 16B per lane; LDS dest is wave-uniform base + lane*16
static __device__ __forceinline__ void gld_lds16(const unsigned short* g, const short* l) {
  typedef const __attribute__((address_space(1))) void* gvp;
  typedef __attribute__((address_space(3))) void* lvp;
  __builtin_amdgcn_global_load_lds((gvp)(uintptr_t)g, (lvp)(unsigned)(uintptr_t)l, 16, 0, 0);
}

// ---------------- fused prep: X fp32->bf16 convert + W1/Wq transposes -------------------
// Grid: dim3(32, 112). y<48: weight transpose. y>=48: X convert.
__global__ __launch_bounds__(256) void prep_k(const float* __restrict__ X,
                                              const float* __restrict__ W1,
                                              const float* __restrict__ Wq,
                                              unsigned short* __restrict__ Xb,
                                              unsigned short* __restrict__ w1t,
                                              unsigned short* __restrict__ wqt) {
  __shared__ float t[32][33];
  if (blockIdx.y >= 48) {
    const int t0 = ((blockIdx.y - 48) * 32 + blockIdx.x) * 256 + threadIdx.x;
    const float4 a = ((const float4*)X)[(size_t)t0 * 2];
    const float4 b = ((const float4*)X)[(size_t)t0 * 2 + 1];
    __align__(16) unsigned short o[8];
    o[0] = f2bf(a.x); o[1] = f2bf(a.y); o[2] = f2bf(a.z); o[3] = f2bf(a.w);
    o[4] = f2bf(b.x); o[5] = f2bf(b.y); o[6] = f2bf(b.z); o[7] = f2bf(b.w);
    *(uint4*)(Xb + (size_t)t0 * 8) = *(const uint4*)o;
    return;
  }
  const bool isW1 = blockIdx.y < 16;
  const float* in = isW1 ? W1 : Wq;
  unsigned short* out = isW1 ? w1t : wqt;
  const int R = isW1 ? DIN : DH;  // rows of source
  const int C = DH;
  const int r0 = (isW1 ? blockIdx.y : (blockIdx.y - 16)) * 32;
  const int c0 = blockIdx.x * 32;
  const int tx = threadIdx.x & 31, ty = threadIdx.x >> 5;  // 32 x 8
  for (int i = ty; i < 32; i += 8) t[i][tx] = in[(size_t)(r0 + i) * C + c0 + tx];
  __syncthreads();
  for (int i = ty; i < 32; i += 8) out[(size_t)(c0 + i) * R + r0 + tx] = f2bf(t[tx][i]);
}

// ---------------- GEMM1: h = relu(xb @ W1 + b1), prefetch-pipelined (T3-minimum) -------
// Double-buffered LDS; next K-tile's global_load_lds issued BEFORE current tile's
// ds_read+MFMA; one __syncthreads (implicit vmcnt(0) drain) per K-step.
__global__ __launch_bounds__(256) void gemm1_k(const unsigned short* __restrict__ Ab,
                                               const unsigned short* __restrict__ Bt,
                                               const float* __restrict__ bias,
                                               unsigned short* __restrict__ outB,
                                               unsigned short* __restrict__ outBT) {
  const int M = BS, N = DH, K = DIN;
  // [buf][half(k 0..31 / 32..63) * 128 rows][32 cols]  => 16 KB per buf per operand
  __shared__ __align__(16) short As[2][2 * 128 * 32];
  __shared__ __align__(16) short Bs[2][2 * 128 * 32];
  const int tid  = threadIdx.x;
  const int m0   = blockIdx.x * 128, n0 = blockIdx.y * 128;
  const int wv   = tid >> 6, lane = tid & 63;
  const int wm   = (wv >> 1) * 64, wn = (wv & 1) * 64;
  const int l16  = lane & 15, quad = lane >> 4;
  const int ra   = lane >> 2, ca = (lane & 3) * 8;  // 16 rows x 32 cols per 1KB wave-call

  const unsigned short* gA = Ab + (size_t)(m0 + wv * 32 + ra) * K + ca;
  const unsigned short* gB = Bt + (size_t)(n0 + wv * 32 + ra) * K + ca;

  floatx4 acc[4][4];
  for (int i = 0; i < 4; i++)
    for (int j = 0; j < 4; j++) acc[i][j] = {0.f, 0.f, 0.f, 0.f};

  auto stage = [&](int buf, int koff) {
    const unsigned short* a = gA + koff;
    const unsigned short* b = gB + koff;
    short* la = &As[buf][wv * 1024];
    gld_lds16(a, la);                          // h0, rows wv*32..+15
    gld_lds16(a + 16 * K, la + 512);           // h0, rows +16..+31
    gld_lds16(a + 32, la + 4096);              // h1, rows wv*32..+15
    gld_lds16(a + 16 * K + 32, la + 4096 + 512);
    short* lb = &Bs[buf][wv * 1024];
    gld_lds16(b, lb);
    gld_lds16(b + 16 * K, lb + 512);
    gld_lds16(b + 32, lb + 4096);
    gld_lds16(b + 16 * K + 32, lb + 4096 + 512);
  };

  stage(0, 0);
  __syncthreads();  // buf0 ready
  const int NK = K / 64;
  for (int ks = 0; ks < NK; ++ks) {
    const int cur = ks & 1;
    if (ks + 1 < NK) stage(cur ^ 1, (ks + 1) * 64);  // prefetch in flight during compute
    const short* Ac = As[cur];
    const short* Bc = Bs[cur];
    bf16x8 af[4], bfr[4];
    #pragma unroll
    for (int h = 0; h < 2; h++) {
      const int ho = h * 4096;
      for (int i = 0; i < 4; i++)
        af[i] = *(const bf16x8*)&Ac[ho + (wm + i * 16 + l16) * 32 + quad * 8];
      for (int j = 0; j < 4; j++)
        bfr[j] = *(const bf16x8*)&Bc[ho + (wn + j * 16 + l16) * 32 + quad * 8];
      __builtin_amdgcn_s_setprio(1);
      for (int i = 0; i < 4; i++)
        for (int j = 0; j < 4; j++)
          acc[i][j] = __builtin_amdgcn_mfma_f32_16x16x32_bf16(af[i], bfr[j], acc[i][j], 0, 0, 0);
      __builtin_amdgcn_s_setprio(0);
    }
    __syncthreads();  // drains prefetch (vmcnt 0) + all LDS reads of cur
  }

  // epilogue: C row = m0+wm+i*16+quad*4+r, col = n0+wn+j*16+l16 (m89-verified C/D layout)
  for (int j = 0; j < 4; j++) {
    const int col = n0 + wn + j * 16 + l16;
    const float bv = bias[col];
    for (int i = 0; i < 4; i++) {
      const int rowb = m0 + wm + i * 16 + quad * 4;
      float v[4];
      for (int r = 0; r < 4; r++) v[r] = fmaxf(acc[i][j][r] + bv, 0.f);
      for (int r = 0; r < 4; r++) outB[(size_t)(rowb + r) * N + col] = f2bf(v[r]);
      ushort4 o4; o4.x = f2bf(v[0]); o4.y = f2bf(v[1]); o4.z = f2bf(v[2]); o4.w = f2bf(v[3]);
      *(ushort4*)(outBT + (size_t)col * M + rowb) = o4;  // transposed copy for attn PV
    }
  }
}

// ---------------- GEMM2: q = h @ Wq, prefetch-pipelined (T3-minimum) --------------------
__global__ __launch_bounds__(256) void gemm2_k(const unsigned short* __restrict__ Ab,
                                               const unsigned short* __restrict__ Bt,
                                               unsigned short* __restrict__ outB) {
  const int N = DH, K = DH;
  __shared__ __align__(16) short As[2][2 * 128 * 32];
  __shared__ __align__(16) short Bs[2][2 * 128 * 32];
  const int tid  = threadIdx.x;
  const int m0   = blockIdx.x * 128, n0 = blockIdx.y * 128;
  const int wv   = tid >> 6, lane = tid & 63;
  const int wm   = (wv >> 1) * 64, wn = (wv & 1) * 64;
  const int l16  = lane & 15, quad = lane >> 4;
  const int ra   = lane >> 2, ca = (lane & 3) * 8;

  const unsigned short* gA = Ab + (size_t)(m0 + wv * 32 + ra) * K + ca;
  const unsigned short* gB = Bt + (size_t)(n0 + wv * 32 + ra) * K + ca;

  floatx4 acc[4][4];
  for (int i = 0; i < 4; i++)
    for (int j = 0; j < 4; j++) acc[i][j] = {0.f, 0.f, 0.f, 0.f};

  auto stage = [&](int buf, int koff) {
    const unsigned short* a = gA + koff;
    const unsigned short* b = gB + koff;
    short* la = &As[buf][wv * 1024];
    gld_lds16(a, la);
    gld_lds16(a + 16 * K, la + 512);
    gld_lds16(a + 32, la + 4096);
    gld_lds16(a + 16 * K + 32, la + 4096 + 512);
    short* lb = &Bs[buf][wv * 1024];
    gld_lds16(b, lb);
    gld_lds16(b + 16 * K, lb + 512);
    gld_lds16(b + 32, lb + 4096);
    gld_lds16(b + 16 * K + 32, lb + 4096 + 512);
  };

  stage(0, 0);
  __syncthreads();
  const int NK = K / 64;
  for (int ks = 0; ks < NK; ++ks) {
    const int cur = ks & 1;
    if (ks + 1 < NK) stage(cur ^ 1, (ks + 1) * 64);
    const short* Ac = As[cur];
    const short* Bc = Bs[cur];
    bf16x8 af[4], bfr[4];
    #pragma unroll
    for (int h = 0; h < 2; h++) {
      const int ho = h * 4096;
      for (int i = 0; i < 4; i++)
        af[i] = *(const bf16x8*)&Ac[ho + (wm + i * 16 + l16) * 32 + quad * 8];
      for (int j = 0; j < 4; j++)
        bfr[j] = *(const bf16x8*)&Bc[ho + (wn + j * 16 + l16) * 32 + quad * 8];
      __builtin_amdgcn_s_setprio(1);
      for (int i = 0; i < 4; i++)
        for (int j = 0; j < 4; j++)
          acc[i][j] = __builtin_amdgcn_mfma_f32_16x16x32_bf16(af[i], bfr[j], acc[i][j], 0, 0, 0);
      __builtin_amdgcn_s_setprio(0);
    }
    __syncthreads();
  }

  for (int j = 0; j < 4; j++) {
    const int col = n0 + wn + j * 16 + l16;
    for (int i = 0; i < 4; i++) {
      const int rowb = m0 + wm + i * 16 + quad * 4;
      for (int r = 0; r < 4; r++)
        outB[(size_t)(rowb + r) * N + col] = f2bf(acc[i][j][r]);
    }
  }
}

// ---------------- banded attention, 16 waves/block ----------------
__global__ __launch_bounds__(1024) void attn_mfma_k(const unsigned short* __restrict__ hb,
                                                    const unsigned short* __restrict__ hbT,
                                                    const unsigned short* __restrict__ qb,
                                                    float* __restrict__ out) {
  __shared__ float Sf[2][32 * 64];             // raw scores, per K-half partials
  __shared__ __align__(16) short Ps[32 * 72];  // softmax weights, row=pos, col=window k

  const int tid  = threadIdx.x;
  const int wave = tid >> 6, lane = tid & 63;
  const int l16  = lane & 15, quad = lane >> 4;
  const int p0   = blockIdx.x * AP;
  const int s0   = p0 & (SEQ - 1);

  for (int i = tid; i < 32 * 72 / 2; i += 1024) ((unsigned*)Ps)[i] = 0;

  // ---------- QK: S[32x64] = q . h_win, K=1024 split across wave pairs ----------
  {
    const int kh = wave & 1;            // K half
    const int nt = (wave >> 1) & 3;     // window col tile
    const int mt = wave >> 3;           // pos row tile
    const unsigned short* qp = qb + (size_t)(p0 + mt * 16 + l16) * DH + kh * 512 + quad * 8;
    const int hrow = s0 - 16 + nt * 16 + l16;          // window row (per-lane)
    const bool hv = (hrow >= 0) && (hrow < SEQ);
    const unsigned short* hp = hb + (long long)(p0 - 16 + nt * 16 + l16) * DH + kh * 512 + quad * 8;

    floatx4 ac[4] = {{0,0,0,0},{0,0,0,0},{0,0,0,0},{0,0,0,0}};
    const bf16x8 hz = {0,0,0,0,0,0,0,0};
    __builtin_amdgcn_s_setprio(1);
    #pragma unroll
    for (int it = 0; it < 16; ++it) {                  // K = 512 per wave
      bf16x8 qa = *(const bf16x8*)(qp + it * 32);
      bf16x8 ha = hz;
      if (hv) ha = *(const bf16x8*)(hp + it * 32);
      ac[it & 3] = __builtin_amdgcn_mfma_f32_16x16x32_bf16(qa, ha, ac[it & 3], 0, 0, 0);
    }
    __builtin_amdgcn_s_setprio(0);
    floatx4 s4;
    for (int r = 0; r < 4; r++)
      s4[r] = (ac[0][r] + ac[1][r]) + (ac[2][r] + ac[3][r]);
    for (int r = 0; r < 4; r++)
      Sf[kh][(mt * 16 + quad * 4 + r) * 64 + nt * 16 + l16] = s4[r] * (1.f / 32.f);
  }
  __syncthreads();

  // ---------- softmax over the 33 band entries jj = row..row+32 ----------
  if (tid < 512) {
    const int row = tid >> 4, k = tid & 15;  // 16 threads per row
    const float v0 = Sf[0][row * 64 + row + k] + Sf[1][row * 64 + row + k];
    const float v1 = Sf[0][row * 64 + row + k + 16] + Sf[1][row * 64 + row + k + 16];
    const float v2 = (k == 0) ? (Sf[0][row * 64 + row + 32] + Sf[1][row * 64 + row + 32]) : -1e30f;
    float mx = fmaxf(v0, fmaxf(v1, v2));
    for (int off = 1; off < 16; off <<= 1) mx = fmaxf(mx, __shfl_xor(mx, off, 64));
    const float e0 = __expf(v0 - mx), e1 = __expf(v1 - mx);
    const float e2 = (k == 0) ? __expf(v2 - mx) : 0.f;
    float sum = e0 + e1 + e2;
    for (int off = 1; off < 16; off <<= 1) sum += __shfl_xor(sum, off, 64);
    const float inv = 1.f / sum;
    Ps[row * 72 + row + k] = f2bf(e0 * inv);
    Ps[row * 72 + row + k + 16] = f2bf(e1 * inv);
    if (k == 0) Ps[row * 72 + row + 32] = f2bf(e2 * inv);
  }
  __syncthreads();

  // ---------- PV (transposed): D[dh, pos] = Hwin^T @ P^T, 4 dh-tiles per wave ----------
  {
    const bf16x8 pb00 = *(const bf16x8*)&Ps[(l16) * 72 + quad * 8];
    const bf16x8 pb01 = *(const bf16x8*)&Ps[(l16) * 72 + 32 + quad * 8];
    const bf16x8 pb10 = *(const bf16x8*)&Ps[(16 + l16) * 72 + quad * 8];
    const bf16x8 pb11 = *(const bf16x8*)&Ps[(16 + l16) * 72 + 32 + quad * 8];

    int lo = 16 - s0; if (lo < 0) lo = 0;              // valid window-k range [lo,hi)
    int hi = SEQ + 16 - s0; if (hi > AW) hi = AW;
    const bool interior = (lo == 0) && (hi == AW);

    #pragma unroll
    for (int i = 0; i < 4; ++i) {
      const int mt2 = wave * 4 + i;  // dh tile (0..63)
      const unsigned short* ap = hbT + (size_t)(mt2 * 16 + l16) * BS + (p0 - 16) + quad * 8;
      bf16x8 aa0 = *(const bf16x8*)(ap);
      bf16x8 aa1 = *(const bf16x8*)(ap + 32);
      if (!interior) {
        #pragma unroll
        for (int j = 0; j < 8; j++) {
          const int k = quad * 8 + j;
          if (k < lo || k >= hi) aa0[j] = 0;
          if (k + 32 < lo || k + 32 >= hi) aa1[j] = 0;
        }
      }
      floatx4 o0 = {0.f, 0.f, 0.f, 0.f}, o1 = {0.f, 0.f, 0.f, 0.f};
      __builtin_amdgcn_s_setprio(1);
      o0 = __builtin_amdgcn_mfma_f32_16x16x32_bf16(aa0, pb00, o0, 0, 0, 0);
      o0 = __builtin_amdgcn_mfma_f32_16x16x32_bf16(aa1, pb01, o0, 0, 0, 0);
      o1 = __builtin_amdgcn_mfma_f32_16x16x32_bf16(aa0, pb10, o1, 0, 0, 0);
      o1 = __builtin_amdgcn_mfma_f32_16x16x32_bf16(aa1, pb11, o1, 0, 0, 0);
      __builtin_amdgcn_s_setprio(0);
      float4 s0v; s0v.x = o0[0]; s0v.y = o0[1]; s0v.z = o0[2]; s0v.w = o0[3];
      float4 s1v; s1v.x = o1[0]; s1v.y = o1[1]; s1v.z = o1[2]; s1v.w = o1[3];
      *(float4*)(out + (size_t)(p0 + l16) * DH + mt2 * 16 + quad * 4) = s0v;
      *(float4*)(out + (size_t)(p0 + 16 + l16) * DH + mt2 * 16 + quad * 4) = s1v;
    }
  }
}

extern "C" void kernel_launch(void* const* d_in, const int* in_sizes, int n_in,
                              void* d_out, int out_size, void* d_ws, size_t ws_size,
                              hipStream_t stream) {
  const float* x  = (const float*)d_in[0];
  const float* W1 = (const float*)d_in[1];
  const float* b1 = (const float*)d_in[2];
  const float* Wq = (const float*)d_in[3];

  // workspace layout (51 MB total)
  char* w = (char*)d_ws;
  unsigned short* w1t = (unsigned short*)(w);                  // 1 MB  W1^T bf16
  unsigned short* wqt = (unsigned short*)(w + (1ull  << 20));  // 2 MB  Wq^T bf16
  unsigned short* hb  = (unsigned short*)(w + (3ull  << 20));  // 16 MB h bf16 row-major
  unsigned short* hbT = (unsigned short*)(w + (19ull << 20));  // 16 MB h bf16 transposed [DH][BS]
  unsigned short* qb  = (unsigned short*)(w + (35ull << 20));  // 16 MB q bf16 row-major
  // xb (8 MB, x in bf16) ALIASES qb: xb is dead before gemm2 writes qb.
  unsigned short* xb  = qb;

  prep_k<<<dim3(32, 112), 256, 0, stream>>>(x, W1, Wq, xb, w1t, wqt);

  // h = relu(xb @ W1 + b1); emits hb + hbT. Grid x = M-tile.
  gemm1_k<<<dim3(BS / 128, DH / 128), 256, 0, stream>>>(xb, w1t, b1, hb, hbT);
  // q = h @ Wq. Grid x = M-tile.
  gemm2_k<<<dim3(BS / 128, DH / 128), 256, 0, stream>>>(hb, wqt, qb);

  attn_mfma_k<<<BS / AP, 1024, 0, stream>>>(hb, hbT, qb, (float*)d_out);
}